// Round 1
// baseline (488.451 us; speedup 1.0000x reference)
//
#include <hip/hip_runtime.h>

#define BATCH 8192
#define NS 16     // samples per solver block
#define PAD 20    // padded leading dim for activation tiles

// ---------------------------------------------------------------------------
// Kernel 1: exact nearest-neighbor (CD=1), replicating reference semantics:
// d = sqrtf(dx*dx) (same rounding as jnp.linalg.norm), argmin with
// first-index tie-break, self excluded.
// ---------------------------------------------------------------------------
__global__ __launch_bounds__(256) void nn_kernel(const float* __restrict__ c,
                                                 float* __restrict__ c0) {
    __shared__ float cs[BATCH];          // 32 KB
    __shared__ float pm[4][64];
    __shared__ int   pj[4][64];
    const int t = threadIdx.x;
    for (int j = t; j < BATCH; j += 256) cs[j] = c[j];
    __syncthreads();
    const int li = t & 63;
    const int i  = blockIdx.x * 64 + li;
    const int p  = t >> 6;               // j-partition 0..3
    const float ci = cs[i];
    float best = 3.0e38f;
    int bestj = 0;
    const int j0 = p * (BATCH / 4);
    for (int j = j0; j < j0 + BATCH / 4; ++j) {
        const float dx = ci - cs[j];
        const float d = sqrtf(dx * dx);
        if ((j != i) && (d < best)) { best = d; bestj = j; }
    }
    pm[p][li] = best;
    pj[p][li] = bestj;
    __syncthreads();
    if (p == 0) {
        for (int q = 1; q < 4; ++q) {     // ascending q keeps smallest index on ties
            const float d = pm[q][li];
            if (d < best) { best = d; bestj = pj[q][li]; }
        }
        c0[i] = cs[bestj];
    }
}

// ---------------------------------------------------------------------------
// Kernel 2: 50-step inner gradient descent.
// grad_y(loss) = forward-mode y-tangent of E(x, y, c0): the JVP (c-tangent)
// term has zero y-gradient through ReLU selects, so it is never computed.
// Block = 256 threads, 16 samples. GEMM mapping: thread = (neuron = t&63,
// 4 samples = (t>>6)*4); fwd + tangent share every weight read.
// ---------------------------------------------------------------------------
__global__ __launch_bounds__(256) void solve_kernel(
    const float* __restrict__ x, const float* __restrict__ c0g,
    const float* __restrict__ W1, const float* __restrict__ b1,
    const float* __restrict__ W2, const float* __restrict__ b2,
    const float* __restrict__ W3, const float* __restrict__ b3,
    const float* __restrict__ W4, float* __restrict__ out)
{
    __shared__ float W2t[64 * 64];       // W2t[k][n] = W2[n][k], 16 KB
    __shared__ float W3t[64 * 64];       // 16 KB
    __shared__ float Z1B[64][PAD];       // x*W1[:,0] + c0*W1[:,2] + b1 per (n,s)
    __shared__ float Ha[64][PAD];        // h1
    __shared__ float Hb[64][PAD];        // dh1, later reused for dh3
    __shared__ float Hc[64][PAD];        // h2
    __shared__ float Hd[64][PAD];        // dh2
    __shared__ float w11s[64], b2s[64], b3s[64], W4s[64];
    __shared__ float yv[NS];

    const int t = threadIdx.x;

    // stage weights (one-time; write conflicts negligible)
    for (int idx = t; idx < 4096; idx += 256) {
        const int n = idx >> 6, k = idx & 63;
        W2t[k * 64 + n] = W2[idx];
        W3t[k * 64 + n] = W3[idx];
    }
    if (t < 64) {
        w11s[t] = W1[t * 3 + 1];
        b2s[t] = b2[t];
        b3s[t] = b3[t];
        W4s[t] = W4[t];
    }
    const int s  = t & 15;               // layer-1 sample
    const int ng = t >> 4;               // layer-1 neuron group
    const int sbase = blockIdx.x * NS;
    {
        const float xs  = x[sbase + s];
        const float cs0 = c0g[sbase + s];
        for (int j = 0; j < 4; ++j) {
            const int n = ng * 4 + j;
            Z1B[n][s] = fmaf(xs, W1[n * 3 + 0], fmaf(cs0, W1[n * 3 + 2], b1[n]));
        }
    }
    if (t < NS) yv[t] = 0.0f;
    __syncthreads();

    const int gn = t & 63;               // gemm neuron
    const int s4 = (t >> 6) * 4;         // gemm sample base (wave-uniform)

    for (int step = 0; step < 50; ++step) {
        // ---- layer 1: z1 = Z1B + y*w11 ----
        {
            const float ys = yv[s];
            for (int j = 0; j < 4; ++j) {
                const int n = ng * 4 + j;
                const float w = w11s[n];
                const float z = fmaf(ys, w, Z1B[n][s]);
                Ha[n][s] = fmaxf(z, 0.0f);
                Hb[n][s] = (z > 0.0f) ? w : 0.0f;   // dh1 = s1 .* W1[:,1]
            }
        }
        __syncthreads();
        // ---- layer 2: (h2, dh2) from (h1, dh1) ----
        {
            const float bb = b2s[gn];
            float z0 = bb, z1 = bb, z2 = bb, z3 = bb;
            float d0 = 0.f, d1 = 0.f, d2 = 0.f, d3 = 0.f;
            #pragma unroll 8
            for (int k = 0; k < 64; ++k) {
                const float w = W2t[k * 64 + gn];
                const float4 h  = *(const float4*)&Ha[k][s4];
                const float4 dh = *(const float4*)&Hb[k][s4];
                z0 = fmaf(w, h.x, z0);  z1 = fmaf(w, h.y, z1);
                z2 = fmaf(w, h.z, z2);  z3 = fmaf(w, h.w, z3);
                d0 = fmaf(w, dh.x, d0); d1 = fmaf(w, dh.y, d1);
                d2 = fmaf(w, dh.z, d2); d3 = fmaf(w, dh.w, d3);
            }
            float4 hv, dv;
            hv.x = fmaxf(z0, 0.f); hv.y = fmaxf(z1, 0.f);
            hv.z = fmaxf(z2, 0.f); hv.w = fmaxf(z3, 0.f);
            dv.x = (z0 > 0.f) ? d0 : 0.f; dv.y = (z1 > 0.f) ? d1 : 0.f;
            dv.z = (z2 > 0.f) ? d2 : 0.f; dv.w = (z3 > 0.f) ? d3 : 0.f;
            *(float4*)&Hc[gn][s4] = hv;
            *(float4*)&Hd[gn][s4] = dv;
        }
        __syncthreads();
        // ---- layer 3: only dh3 needed (E0 itself never used) ----
        {
            const float bb = b3s[gn];
            float z0 = bb, z1 = bb, z2 = bb, z3 = bb;
            float d0 = 0.f, d1 = 0.f, d2 = 0.f, d3 = 0.f;
            #pragma unroll 8
            for (int k = 0; k < 64; ++k) {
                const float w = W3t[k * 64 + gn];
                const float4 h  = *(const float4*)&Hc[k][s4];
                const float4 dh = *(const float4*)&Hd[k][s4];
                z0 = fmaf(w, h.x, z0);  z1 = fmaf(w, h.y, z1);
                z2 = fmaf(w, h.z, z2);  z3 = fmaf(w, h.w, z3);
                d0 = fmaf(w, dh.x, d0); d1 = fmaf(w, dh.y, d1);
                d2 = fmaf(w, dh.z, d2); d3 = fmaf(w, dh.w, d3);
            }
            float4 dv;
            dv.x = (z0 > 0.f) ? d0 : 0.f; dv.y = (z1 > 0.f) ? d1 : 0.f;
            dv.z = (z2 > 0.f) ? d2 : 0.f; dv.w = (z3 > 0.f) ? d3 : 0.f;
            *(float4*)&Hb[gn][s4] = dv;   // dh3 reuses dh1's buffer
        }
        __syncthreads();
        // ---- layer 4 + y update: g = W4 . dh3 ----
        if (t < 128) {
            const int q  = t & 7;         // 8 lanes per sample
            const int ss = t >> 3;        // sample 0..15
            float g = 0.f;
            #pragma unroll
            for (int u = 0; u < 8; ++u) {
                const int n = q + 8 * u;  // (20q+s)%32 spread -> ~2-way, free
                g = fmaf(W4s[n], Hb[n][ss], g);
            }
            g += __shfl_xor(g, 1);
            g += __shfl_xor(g, 2);
            g += __shfl_xor(g, 4);
            if (q == 0) yv[ss] = yv[ss] - 0.1f * g;
        }
        __syncthreads();
    }
    if (t < NS) out[sbase + t] = yv[t];
}

extern "C" void kernel_launch(void* const* d_in, const int* in_sizes, int n_in,
                              void* d_out, int out_size, void* d_ws, size_t ws_size,
                              hipStream_t stream) {
    const float* x  = (const float*)d_in[0];
    const float* c  = (const float*)d_in[1];
    const float* W1 = (const float*)d_in[2];
    const float* b1 = (const float*)d_in[3];
    const float* W2 = (const float*)d_in[4];
    const float* b2 = (const float*)d_in[5];
    const float* W3 = (const float*)d_in[6];
    const float* b3 = (const float*)d_in[7];
    const float* W4 = (const float*)d_in[8];
    // d_in[9] = b4: unused (only grad wrt y is needed, b4 drops out)
    float* c0  = (float*)d_ws;            // 8192 floats of scratch
    float* out = (float*)d_out;

    nn_kernel<<<BATCH / 64, 256, 0, stream>>>(c, c0);
    solve_kernel<<<BATCH / NS, 256, 0, stream>>>(x, c0, W1, b1, W2, b2, W3, b3, W4, out);
}

// Round 2
// 431.575 us; speedup vs baseline: 1.1318x; 1.1318x over previous
//
#include <hip/hip_runtime.h>

#define BATCH 8192
#define NS 16     // samples per solver block
#define PAD 20    // padded leading dim for activation tiles

// ---------------------------------------------------------------------------
// Kernel 1 (v2): exact nearest-neighbor (CD=1), parallel over 16 lanes per i.
// Reference semantics preserved: d = sqrtf(dx*dx), argmin with first-index
// tie-break (lexicographic (d, j) merges), self excluded.
// 512 blocks x 256 threads; 16 i's per block; lane-group of 16 per i.
// ---------------------------------------------------------------------------
__global__ __launch_bounds__(256) void nn_kernel(const float* __restrict__ c,
                                                 float* __restrict__ c0) {
    __shared__ float cs[BATCH];          // 32 KB
    const int t = threadIdx.x;
    for (int j = t; j < BATCH; j += 256) cs[j] = c[j];
    __syncthreads();
    const int part = t & 15;             // j-partition lane within group (same wave)
    const int il   = t >> 4;             // i-local 0..15
    const int i    = blockIdx.x * 16 + il;
    const float ci = cs[i];
    // 4 independent chains for ILP; chain r covers j = part + 16*(128r..128r+127)
    // (strictly increasing j within and across chains for a fixed part)
    float bd0 = 3e38f, bd1 = 3e38f, bd2 = 3e38f, bd3 = 3e38f;
    int   bj0 = 0,     bj1 = 0,     bj2 = 0,     bj3 = 0;
    #pragma unroll 4
    for (int jj = 0; jj < 128; ++jj) {
        const int ja = part + (jj << 4);
        const int jb = ja + (128 << 4);
        const int jc = ja + (256 << 4);
        const int jd = ja + (384 << 4);
        float da = sqrtf((ci - cs[ja]) * (ci - cs[ja]));
        float db = sqrtf((ci - cs[jb]) * (ci - cs[jb]));
        float dc = sqrtf((ci - cs[jc]) * (ci - cs[jc]));
        float dd = sqrtf((ci - cs[jd]) * (ci - cs[jd]));
        if (ja == i) da = 3e38f;
        if (jb == i) db = 3e38f;
        if (jc == i) dc = 3e38f;
        if (jd == i) dd = 3e38f;
        if (da < bd0) { bd0 = da; bj0 = ja; }   // strict < + ascending j = first-min
        if (db < bd1) { bd1 = db; bj1 = jb; }
        if (dc < bd2) { bd2 = dc; bj2 = jc; }
        if (dd < bd3) { bd3 = dd; bj3 = jd; }
    }
    float best = bd0; int bestj = bj0;
    if (bd1 < best || (bd1 == best && bj1 < bestj)) { best = bd1; bestj = bj1; }
    if (bd2 < best || (bd2 == best && bj2 < bestj)) { best = bd2; bestj = bj2; }
    if (bd3 < best || (bd3 == best && bj3 < bestj)) { best = bd3; bestj = bj3; }
    // reduce over the 16 consecutive lanes sharing il (same wave)
    #pragma unroll
    for (int off = 1; off < 16; off <<= 1) {
        const float od = __shfl_xor(best, off);
        const int   oj = __shfl_xor(bestj, off);
        if (od < best || (od == best && oj < bestj)) { best = od; bestj = oj; }
    }
    if (part == 0) c0[i] = cs[bestj];
}

// ---------------------------------------------------------------------------
// Kernel 2 (v2): 50-step inner gradient descent, 3 barriers/step, all 256
// threads active in every phase. grad_y(loss) = y-tangent of E(x,y,c0): the
// c-tangent (JVP) term has zero y-gradient through ReLU selects.
// y is replicated in registers (all threads sharing a sample compute the
// identical update -> bit-consistent, no LDS round-trip, no extra barrier).
// ---------------------------------------------------------------------------
__global__ __launch_bounds__(256) void solve_kernel(
    const float* __restrict__ x, const float* __restrict__ c0g,
    const float* __restrict__ W1, const float* __restrict__ b1,
    const float* __restrict__ W2, const float* __restrict__ b2,
    const float* __restrict__ W3, const float* __restrict__ b3,
    const float* __restrict__ W4, float* __restrict__ out)
{
    __shared__ float W2t[64 * 64];       // W2t[k][n] = W2[n][k], 16 KB
    __shared__ float W3t[64 * 64];       // 16 KB
    __shared__ float A1[64][PAD];        // x*W1[:,0] + c0*W1[:,2] + b1
    __shared__ float Ha[64][PAD];        // h1
    __shared__ float Hb[64][PAD];        // dh1
    __shared__ float Hc[64][PAD];        // h2
    __shared__ float Hd[64][PAD];        // dh2
    __shared__ float He[64][PAD];        // dh3 (own buffer: no hazard in fused phase)
    __shared__ float w11s[64], b2s[64], b3s[64], W4s[64];

    const int t = threadIdx.x;

    for (int idx = t; idx < 4096; idx += 256) {
        const int n = idx >> 6, k = idx & 63;
        W2t[k * 64 + n] = W2[idx];
        W3t[k * 64 + n] = W3[idx];
    }
    if (t < 64) {
        w11s[t] = W1[t * 3 + 1];
        b2s[t] = b2[t];
        b3s[t] = b3[t];
        W4s[t] = W4[t];
    }
    const int s  = t & 15;               // this thread's sample (layer1/4 phases)
    const int ng = t >> 4;               // 0..15, neuron group for layer 1
    const int sbase = blockIdx.x * NS;
    {
        const float xs = x[sbase + s];
        const float cc = c0g[sbase + s];
        #pragma unroll
        for (int j = 0; j < 4; ++j) {
            const int n = ng * 4 + j;
            A1[n][s] = fmaf(xs, W1[n * 3 + 0], fmaf(cc, W1[n * 3 + 2], b1[n]));
        }
    }
    __syncthreads();

    const int gn  = t & 63;              // gemm neuron
    const int s4  = (t >> 6) * 4;        // gemm sample base (wave-uniform)
    const int ng2 = (t >> 4) & 3;        // layer-4 partial-sum slice

    float y = 0.0f;

    // initial layer 1 (y = 0)
    #pragma unroll
    for (int j = 0; j < 4; ++j) {
        const int n = ng * 4 + j;
        const float w = w11s[n];
        const float z = fmaf(y, w, A1[n][s]);
        Ha[n][s] = fmaxf(z, 0.0f);
        Hb[n][s] = (z > 0.0f) ? w : 0.0f;
    }
    __syncthreads();

    for (int step = 0; step < 50; ++step) {
        // ---- layer 2: (h2, dh2) ----
        {
            const float bb = b2s[gn];
            float z0 = bb, z1 = bb, z2 = bb, z3 = bb;
            float d0 = 0.f, d1 = 0.f, d2 = 0.f, d3 = 0.f;
            #pragma unroll 16
            for (int k = 0; k < 64; ++k) {
                const float w = W2t[k * 64 + gn];
                const float4 h  = *(const float4*)&Ha[k][s4];
                const float4 dh = *(const float4*)&Hb[k][s4];
                z0 = fmaf(w, h.x, z0);  z1 = fmaf(w, h.y, z1);
                z2 = fmaf(w, h.z, z2);  z3 = fmaf(w, h.w, z3);
                d0 = fmaf(w, dh.x, d0); d1 = fmaf(w, dh.y, d1);
                d2 = fmaf(w, dh.z, d2); d3 = fmaf(w, dh.w, d3);
            }
            float4 hv, dv;
            hv.x = fmaxf(z0, 0.f); hv.y = fmaxf(z1, 0.f);
            hv.z = fmaxf(z2, 0.f); hv.w = fmaxf(z3, 0.f);
            dv.x = (z0 > 0.f) ? d0 : 0.f; dv.y = (z1 > 0.f) ? d1 : 0.f;
            dv.z = (z2 > 0.f) ? d2 : 0.f; dv.w = (z3 > 0.f) ? d3 : 0.f;
            *(float4*)&Hc[gn][s4] = hv;
            *(float4*)&Hd[gn][s4] = dv;
        }
        __syncthreads();
        // ---- layer 3: dh3 only ----
        {
            const float bb = b3s[gn];
            float z0 = bb, z1 = bb, z2 = bb, z3 = bb;
            float d0 = 0.f, d1 = 0.f, d2 = 0.f, d3 = 0.f;
            #pragma unroll 16
            for (int k = 0; k < 64; ++k) {
                const float w = W3t[k * 64 + gn];
                const float4 h  = *(const float4*)&Hc[k][s4];
                const float4 dh = *(const float4*)&Hd[k][s4];
                z0 = fmaf(w, h.x, z0);  z1 = fmaf(w, h.y, z1);
                z2 = fmaf(w, h.z, z2);  z3 = fmaf(w, h.w, z3);
                d0 = fmaf(w, dh.x, d0); d1 = fmaf(w, dh.y, d1);
                d2 = fmaf(w, dh.z, d2); d3 = fmaf(w, dh.w, d3);
            }
            float4 dv;
            dv.x = (z0 > 0.f) ? d0 : 0.f; dv.y = (z1 > 0.f) ? d1 : 0.f;
            dv.z = (z2 > 0.f) ? d2 : 0.f; dv.w = (z3 > 0.f) ? d3 : 0.f;
            *(float4*)&He[gn][s4] = dv;
        }
        __syncthreads();
        // ---- fused: layer 4 (g for own sample) + y update + next layer 1 ----
        {
            float g = 0.f;
            #pragma unroll
            for (int i = 0; i < 16; ++i) {
                const int n = ng2 + 4 * i;     // bank spread ~2-way (free)
                g = fmaf(W4s[n], He[n][s], g);
            }
            // butterfly over the 4 lanes sharing s (ng2 in bits 4..5):
            // all lanes end with the identical sum -> consistent y everywhere
            g += __shfl_xor(g, 16);
            g += __shfl_xor(g, 32);
            y = y - 0.1f * g;
        }
        if (step < 49) {
            #pragma unroll
            for (int j = 0; j < 4; ++j) {
                const int n = ng * 4 + j;
                const float w = w11s[n];
                const float z = fmaf(y, w, A1[n][s]);
                Ha[n][s] = fmaxf(z, 0.0f);
                Hb[n][s] = (z > 0.0f) ? w : 0.0f;
            }
            __syncthreads();
        }
    }
    if (t < NS) out[sbase + t] = y;
}

extern "C" void kernel_launch(void* const* d_in, const int* in_sizes, int n_in,
                              void* d_out, int out_size, void* d_ws, size_t ws_size,
                              hipStream_t stream) {
    const float* x  = (const float*)d_in[0];
    const float* c  = (const float*)d_in[1];
    const float* W1 = (const float*)d_in[2];
    const float* b1 = (const float*)d_in[3];
    const float* W2 = (const float*)d_in[4];
    const float* b2 = (const float*)d_in[5];
    const float* W3 = (const float*)d_in[6];
    const float* b3 = (const float*)d_in[7];
    const float* W4 = (const float*)d_in[8];
    // d_in[9] = b4: unused (only grad wrt y is needed, b4 drops out)
    float* c0  = (float*)d_ws;            // 8192 floats of scratch
    float* out = (float*)d_out;

    nn_kernel<<<BATCH / 16, 256, 0, stream>>>(c, c0);
    solve_kernel<<<BATCH / NS, 256, 0, stream>>>(x, c0, W1, b1, W2, b2, W3, b3, W4, out);
}

// Round 4
// 193.197 us; speedup vs baseline: 2.5283x; 2.2339x over previous
//
#include <hip/hip_runtime.h>

#define BATCH 8192
#define LOSC  2048.0f
#define LOINV (1.0f / 2048.0f)

typedef _Float16 f16x8 __attribute__((ext_vector_type(8)));
typedef _Float16 f16x2 __attribute__((ext_vector_type(2)));
typedef float    f32x4 __attribute__((ext_vector_type(4)));

union PK2 { f16x2 h; unsigned u; };
union U8  { f16x8 v; unsigned u[4]; };

__device__ __forceinline__ unsigned pack2(float a, float b) {
    PK2 p; p.h[0] = (_Float16)a; p.h[1] = (_Float16)b; return p.u;
}

// ---------------------------------------------------------------------------
// Kernel 1 (v4): exact NN (CD=1). Reference per-element distance is
// sqrt(fl(dx*dx)) which equals |dx| exactly in correctly-rounded fp32, so we
// compare fabsf(dx): bitwise-identical ordering AND tie semantics
// (first-index argmin via strict < over ascending j). Self excluded.
// ---------------------------------------------------------------------------
__global__ __launch_bounds__(256) void nn_kernel(const float* __restrict__ c,
                                                 float* __restrict__ c0) {
    __shared__ float cs[BATCH];          // 32 KB
    const int t = threadIdx.x;
    {
        const float4* cg = (const float4*)c;
        float4* cl = (float4*)cs;
        for (int j = t; j < BATCH / 4; j += 256) cl[j] = cg[j];
    }
    __syncthreads();
    const int part = t & 31;
    const int i    = blockIdx.x * 8 + (t >> 5);
    const float ci = cs[i];
    const int sj0 = ((i & 3) == 0) ? (i >> 2) : -1;
    const int sj1 = ((i & 3) == 1) ? (i >> 2) : -1;
    const int sj2 = ((i & 3) == 2) ? (i >> 2) : -1;
    const int sj3 = ((i & 3) == 3) ? (i >> 2) : -1;
    const float4* cs4 = (const float4*)cs;
    float bd0 = 3e38f, bd1 = 3e38f, bd2 = 3e38f, bd3 = 3e38f;
    int   bj0 = 0,     bj1 = 0,     bj2 = 0,     bj3 = 0;
    #pragma unroll 4
    for (int tt = 0; tt < 64; ++tt) {
        const int jj = part + (tt << 5);
        const float4 v = cs4[jj];
        float d0 = fabsf(ci - v.x);
        float d1 = fabsf(ci - v.y);
        float d2 = fabsf(ci - v.z);
        float d3 = fabsf(ci - v.w);
        if (jj == sj0) d0 = 3e38f;
        if (jj == sj1) d1 = 3e38f;
        if (jj == sj2) d2 = 3e38f;
        if (jj == sj3) d3 = 3e38f;
        if (d0 < bd0) { bd0 = d0; bj0 = jj; }
        if (d1 < bd1) { bd1 = d1; bj1 = jj; }
        if (d2 < bd2) { bd2 = d2; bj2 = jj; }
        if (d3 < bd3) { bd3 = d3; bj3 = jj; }
    }
    float best = bd0; int bestj = bj0 * 4 + 0;
    { const int j1 = bj1 * 4 + 1; if (bd1 < best || (bd1 == best && j1 < bestj)) { best = bd1; bestj = j1; } }
    { const int j2 = bj2 * 4 + 2; if (bd2 < best || (bd2 == best && j2 < bestj)) { best = bd2; bestj = j2; } }
    { const int j3 = bj3 * 4 + 3; if (bd3 < best || (bd3 == best && j3 < bestj)) { best = bd3; bestj = j3; } }
    #pragma unroll
    for (int off = 1; off < 32; off <<= 1) {
        const float od = __shfl_xor(best, off);
        const int   oj = __shfl_xor(bestj, off);
        if (od < best || (od == best && oj < bestj)) { best = od; bestj = oj; }
    }
    if (part == 0) c0[i] = cs[bestj];
}

// ---------------------------------------------------------------------------
// Kernel 2 (v4): one wave = 8 samples; split-f16 MFMA (hi/lo, lo scaled 2^11)
// for fp32-class accuracy at MFMA rate. B cols = [8 fwd | 8 tangent].
// W-hi fragments in registers; W-lo matrices + biases in LDS (register
// budget); in-loop __syncthreads() fences LICM from hoisting the
// loop-invariant LDS fragment reads into registers (would spill).
// mfma_f32_16x16x32_f16: A[m=lane&15][k=q*8+j], B[k=q*8+j][n=lane&15],
// C/D col=lane&15, row=q*4+reg (m89-verified family).
// ---------------------------------------------------------------------------
__global__ __launch_bounds__(64) void solve_kernel(
    const float* __restrict__ x, const float* __restrict__ c0g,
    const float* __restrict__ W1, const float* __restrict__ b1,
    const float* __restrict__ W2, const float* __restrict__ b2,
    const float* __restrict__ W3, const float* __restrict__ b3,
    const float* __restrict__ W4, float* __restrict__ out)
{
    __shared__ __align__(16) _Float16 WL2[64][72];   // lo(W2)*2^11, padded
    __shared__ __align__(16) _Float16 WL3[64][72];
    __shared__ float b2s[64], b3s[64];

    const int lane = threadIdx.x & 63;
    const int q  = lane >> 4;
    const int cc = lane & 15;
    const bool fwd = (cc < 8);
    const int s = cc & 7;
    const int sbase = blockIdx.x * 8;

    // ---- stage: lo-weights -> LDS, biases -> LDS ----
    #pragma unroll 4
    for (int n = 0; n < 64; ++n) {
        const float w2 = W2[n * 64 + lane];
        const float w3 = W3[n * 64 + lane];
        const _Float16 h2 = (_Float16)w2;
        const _Float16 h3 = (_Float16)w3;
        WL2[n][lane] = (_Float16)((w2 - (float)h2) * LOSC);
        WL3[n][lane] = (_Float16)((w3 - (float)h3) * LOSC);
    }
    b2s[lane] = b2[lane];
    b3s[lane] = b3[lane];

    // ---- hi-weight fragments (registers, all 50 steps) ----
    f16x8 W2h[4][2], W3h[4][2];
    #pragma unroll
    for (int T = 0; T < 4; ++T)
        #pragma unroll
        for (int ch = 0; ch < 2; ++ch) {
            const float* p2 = W2 + (T * 16 + cc) * 64 + ch * 32 + q * 8;
            const float* p3 = W3 + (T * 16 + cc) * 64 + ch * 32 + q * 8;
            f16x8 f2, f3;
            #pragma unroll
            for (int e = 0; e < 8; ++e) { f2[e] = (_Float16)p2[e]; f3[e] = (_Float16)p3[e]; }
            W2h[T][ch] = f2;
            W3h[T][ch] = f3;
        }

    float w4r[16];
    #pragma unroll
    for (int T = 0; T < 4; ++T)
        #pragma unroll
        for (int r = 0; r < 4; ++r)
            w4r[T * 4 + r] = W4[T * 16 + q * 4 + r];

    // ---- layer-1 constants: rows k = ch*32 + q*8 + j, this lane's sample ----
    float A1v[16], w11v[16];
    {
        const float xs  = x[sbase + s];
        const float c0s = c0g[sbase + s];
        #pragma unroll
        for (int ch = 0; ch < 2; ++ch)
            #pragma unroll
            for (int j = 0; j < 8; ++j) {
                const int k = ch * 32 + q * 8 + j;
                w11v[ch * 8 + j] = W1[k * 3 + 1];
                A1v[ch * 8 + j]  = fmaf(xs, W1[k * 3 + 0],
                                        fmaf(c0s, W1[k * 3 + 2], b1[k]));
            }
    }
    __syncthreads();

    const int srcA = ((q & 1) * 2) * 16 + cc;   // quad (q&1)*2, same column
    const int srcB = srcA + 16;                 // next quad
    const bool hiT = (q >> 1) != 0;

    float y = 0.0f;

    for (int step = 0; step < 50; ++step) {
        __syncthreads();   // single-wave block: ~free; fences LDS-read hoisting
        // ---- layer 1 (fp32) -> split B1 fragments ----
        U8 B1h[2], B1l[2];
        #pragma unroll
        for (int ch = 0; ch < 2; ++ch)
            #pragma unroll
            for (int j = 0; j < 8; ++j) {
                const float w = w11v[ch * 8 + j];
                const float z = fmaf(y, w, A1v[ch * 8 + j]);
                const float v = fwd ? fmaxf(z, 0.f) : (z > 0.f ? w : 0.f);
                const _Float16 vh = (_Float16)v;
                B1h[ch].v[j] = vh;
                B1l[ch].v[j] = (_Float16)((v - (float)vh) * LOSC);
            }
        // ---- layer 2: split MFMA ----
        f32x4 ZH[4], ZL[4];
        #pragma unroll
        for (int T = 0; T < 4; ++T) {
            const float4 bv = *(const float4*)&b2s[T * 16 + q * 4];
            f32x4 aH;
            aH[0] = fwd ? bv.x : 0.f; aH[1] = fwd ? bv.y : 0.f;
            aH[2] = fwd ? bv.z : 0.f; aH[3] = fwd ? bv.w : 0.f;
            aH = __builtin_amdgcn_mfma_f32_16x16x32_f16(W2h[T][0], B1h[0].v, aH, 0, 0, 0);
            aH = __builtin_amdgcn_mfma_f32_16x16x32_f16(W2h[T][1], B1h[1].v, aH, 0, 0, 0);
            f32x4 aL = {0.f, 0.f, 0.f, 0.f};
            aL = __builtin_amdgcn_mfma_f32_16x16x32_f16(W2h[T][0], B1l[0].v, aL, 0, 0, 0);
            aL = __builtin_amdgcn_mfma_f32_16x16x32_f16(W2h[T][1], B1l[1].v, aL, 0, 0, 0);
            const f16x8 l0 = *(const f16x8*)&WL2[T * 16 + cc][q * 8];
            const f16x8 l1 = *(const f16x8*)&WL2[T * 16 + cc][32 + q * 8];
            aL = __builtin_amdgcn_mfma_f32_16x16x32_f16(l0, B1h[0].v, aL, 0, 0, 0);
            aL = __builtin_amdgcn_mfma_f32_16x16x32_f16(l1, B1h[1].v, aL, 0, 0, 0);
            ZH[T] = aH; ZL[T] = aL;
        }
        // ---- combine + mask + split + C->B shfl transform ----
        unsigned pkh[4][2], pkl[4][2];
        #pragma unroll
        for (int T = 0; T < 4; ++T) {
            float vh4[4], vl4[4];
            #pragma unroll
            for (int r = 0; r < 4; ++r) {
                const float z = fmaf(ZL[T][r], LOINV, ZH[T][r]);
                const float recv = __shfl_xor(z, 8);
                const float v = fwd ? fmaxf(z, 0.f) : (recv > 0.f ? z : 0.f);
                const _Float16 vh = (_Float16)v;
                vh4[r] = (float)vh;
                vl4[r] = (v - (float)vh) * LOSC;
            }
            pkh[T][0] = pack2(vh4[0], vh4[1]); pkh[T][1] = pack2(vh4[2], vh4[3]);
            pkl[T][0] = pack2(vl4[0], vl4[1]); pkl[T][1] = pack2(vl4[2], vl4[3]);
        }
        U8 B2h[2], B2l[2];
        #pragma unroll
        for (int ch = 0; ch < 2; ++ch)
            #pragma unroll
            for (int p = 0; p < 2; ++p) {
                const unsigned haL = (unsigned)__shfl((int)pkh[ch * 2][p],     srcA);
                const unsigned haH = (unsigned)__shfl((int)pkh[ch * 2 + 1][p], srcA);
                const unsigned hbL = (unsigned)__shfl((int)pkh[ch * 2][p],     srcB);
                const unsigned hbH = (unsigned)__shfl((int)pkh[ch * 2 + 1][p], srcB);
                const unsigned laL = (unsigned)__shfl((int)pkl[ch * 2][p],     srcA);
                const unsigned laH = (unsigned)__shfl((int)pkl[ch * 2 + 1][p], srcA);
                const unsigned lbL = (unsigned)__shfl((int)pkl[ch * 2][p],     srcB);
                const unsigned lbH = (unsigned)__shfl((int)pkl[ch * 2 + 1][p], srcB);
                B2h[ch].u[p]     = hiT ? haH : haL;
                B2h[ch].u[2 + p] = hiT ? hbH : hbL;
                B2l[ch].u[p]     = hiT ? laH : laL;
                B2l[ch].u[2 + p] = hiT ? lbH : lbL;
            }
        // ---- layer 3: split MFMA ----
        #pragma unroll
        for (int T = 0; T < 4; ++T) {
            const float4 bv = *(const float4*)&b3s[T * 16 + q * 4];
            f32x4 aH;
            aH[0] = fwd ? bv.x : 0.f; aH[1] = fwd ? bv.y : 0.f;
            aH[2] = fwd ? bv.z : 0.f; aH[3] = fwd ? bv.w : 0.f;
            aH = __builtin_amdgcn_mfma_f32_16x16x32_f16(W3h[T][0], B2h[0].v, aH, 0, 0, 0);
            aH = __builtin_amdgcn_mfma_f32_16x16x32_f16(W3h[T][1], B2h[1].v, aH, 0, 0, 0);
            f32x4 aL = {0.f, 0.f, 0.f, 0.f};
            aL = __builtin_amdgcn_mfma_f32_16x16x32_f16(W3h[T][0], B2l[0].v, aL, 0, 0, 0);
            aL = __builtin_amdgcn_mfma_f32_16x16x32_f16(W3h[T][1], B2l[1].v, aL, 0, 0, 0);
            const f16x8 l0 = *(const f16x8*)&WL3[T * 16 + cc][q * 8];
            const f16x8 l1 = *(const f16x8*)&WL3[T * 16 + cc][32 + q * 8];
            aL = __builtin_amdgcn_mfma_f32_16x16x32_f16(l0, B2h[0].v, aL, 0, 0, 0);
            aL = __builtin_amdgcn_mfma_f32_16x16x32_f16(l1, B2h[1].v, aL, 0, 0, 0);
            ZH[T] = aH; ZL[T] = aL;
        }
        // ---- layer 4 (fp32): g = W4 . (1[z3>0] * dz3) ----
        float g = 0.f;
        #pragma unroll
        for (int T = 0; T < 4; ++T)
            #pragma unroll
            for (int r = 0; r < 4; ++r) {
                const float z = fmaf(ZL[T][r], LOINV, ZH[T][r]);
                const float recv  = __shfl_xor(z, 8);
                const float maskv = fwd ? z : recv;   // z3 fwd (with bias)
                const float valv  = fwd ? recv : z;   // dz3
                g = fmaf(w4r[T * 4 + r], (maskv > 0.f) ? valv : 0.f, g);
            }
        g += __shfl_xor(g, 16);   // sum over quads (bitwise-uniform per sample)
        g += __shfl_xor(g, 32);
        y -= 0.1f * g;
    }
    if (lane < 8) out[sbase + lane] = y;
}

extern "C" void kernel_launch(void* const* d_in, const int* in_sizes, int n_in,
                              void* d_out, int out_size, void* d_ws, size_t ws_size,
                              hipStream_t stream) {
    const float* x  = (const float*)d_in[0];
    const float* c  = (const float*)d_in[1];
    const float* W1 = (const float*)d_in[2];
    const float* b1 = (const float*)d_in[3];
    const float* W2 = (const float*)d_in[4];
    const float* b2 = (const float*)d_in[5];
    const float* W3 = (const float*)d_in[6];
    const float* b3 = (const float*)d_in[7];
    const float* W4 = (const float*)d_in[8];
    // d_in[9] = b4: unused (only grad wrt y is needed, b4 drops out)
    float* c0  = (float*)d_ws;
    float* out = (float*)d_out;

    nn_kernel<<<BATCH / 8, 256, 0, stream>>>(c, c0);
    solve_kernel<<<BATCH / 8, 64, 0, stream>>>(x, c0, W1, b1, W2, b2, W3, b3, W4, out);
}